// Round 3
// baseline (213.501 us; speedup 1.0000x reference)
//
#include <hip/hip_runtime.h>

// Fused DressedQuantumNet:
//   pre = in[65536,512] @ W_pre.T[512,4] + b_pre          (memory-bound: 134 MB read)
//   q_in = tanh(pre) * pi/2
//   q_out = 4-qubit circuit (16 real amplitudes)
//   out = q_out @ W_post.T[4,200] + b_post                (52 MB write)
//
// Block=256 (4 waves), wave owns 4 samples, grid = B/16 = 4096 (generation
// overlap: young blocks stream Phase-A reads while retiring blocks run B/C).
//
// Phase B is AMPLITUDE-PER-LANE: 16 lanes hold one sample's 16 amplitudes,
// 4 samples per wave -> all 64 lanes busy. RY = shfl_xor + sign-select + fma;
// CNOT = shfl_xor + cndmask; all four <Z_q> via one signed Walsh-Hadamard
// butterfly (4 shfl).
//
// R3 A/B: input loads are PLAIN (cacheable) instead of nontemporal. The
// 134 MB input fits in the 256 MB Infinity Cache; if the harness's poison
// fills don't thrash L3, cross-iteration residency cuts read time ~2x.
// Output stores remain nontemporal (written once, never re-read here).

#define BLOCK 256
#define WS 4             // samples per wave
#define SPB 16           // samples per block

typedef float f4 __attribute__((ext_vector_type(4)));

// tanh(x) = 1 - 2/(exp(2x)+1); hw v_exp + v_rcp. Error ~ulp vs 1.5e-2 budget.
__device__ __forceinline__ float fast_tanh(float x) {
  const float e = __expf(2.0f * x);
  return 1.0f - 2.0f * __builtin_amdgcn_rcpf(e + 1.0f);
}

// One reduce-scatter step at xor-mask m. v0 = copy with bit==0, v1 = bit==1.
// Lane keeps the copy matching (lane&m), sends the other.
__device__ __forceinline__ float rs_step(float v0, float v1, bool hi, int m) {
  const float sd = hi ? v0 : v1;
  const float kp = hi ? v1 : v0;
  return kp + __shfl_xor(sd, m, 64);
}

__global__ __launch_bounds__(BLOCK, 4) void dqnet_kernel(
    const float* __restrict__ in, const float* __restrict__ Wpre,
    const float* __restrict__ bpre, const float* __restrict__ qp,
    const float* __restrict__ Wpost, const float* __restrict__ bpost,
    float* __restrict__ out) {
  __shared__ float s_wpost[200 * 4];   // [j][q]
  __shared__ float s_bpost[200];
  __shared__ f4 s_c4[6], s_s4[6];      // cos/sin(qw[k,q]/2), f4 per layer
  __shared__ f4 s_qout[SPB];           // [sample_local] -> (z0,z1,z2,z3)

  const int tid = threadIdx.x;
  const int lane = tid & 63;
  const int wave = tid >> 6;

  // ---- setup: stage W_post/b_post and circuit-layer sincos into LDS ----
  if (tid < 200) {
    ((f4*)s_wpost)[tid] = ((const f4*)Wpost)[tid];
    s_bpost[tid] = bpost[tid];
  } else if (tid < 224) {
    const int k = tid - 200;
    const float a = qp[k] * 0.5f;
    ((float*)s_c4)[k] = __cosf(a);
    ((float*)s_s4)[k] = __sinf(a);
  }

  // per-lane bias for its angle slot (4 floats, L1-hit)
  const float bpre_a = bpre[lane & 3];

  // Per-lane W_pre fragment: features [lane*4, lane*4+4) and +256.
  f4 wa[4], wb[4];
  #pragma unroll
  for (int q = 0; q < 4; ++q) {
    wa[q] = *(const f4*)(Wpre + q * 512 + lane * 4);
    wb[q] = *(const f4*)(Wpre + q * 512 + 256 + lane * 4);
  }

  // ---- Phase A: pre-GEMV, depth-2 prefetch ring, per-lane partials ----
  const int tile = blockIdx.x * SPB + wave * WS;
  const float* rb = in + (size_t)tile * 512 + lane * 4;

  const bool b1 = (lane & 1) != 0;
  const bool b2 = (lane & 2) != 0;

  float part[WS];
  f4 pxa[2], pxb[2];
  pxa[0] = *(const f4*)(rb);        pxb[0] = *(const f4*)(rb + 256);
  pxa[1] = *(const f4*)(rb + 512);  pxb[1] = *(const f4*)(rb + 512 + 256);
  #pragma unroll
  for (int s = 0; s < WS; ++s) {
    const f4 xa = pxa[s & 1], xb = pxb[s & 1];
    if (s + 2 < WS) {                 // refill ring slot two ahead
      pxa[s & 1] = *(const f4*)(rb + (size_t)(s + 2) * 512);
      pxb[s & 1] = *(const f4*)(rb + (size_t)(s + 2) * 512 + 256);
    }
    float p0 = xa.x*wa[0].x + xa.y*wa[0].y + xa.z*wa[0].z + xa.w*wa[0].w
             + xb.x*wb[0].x + xb.y*wb[0].y + xb.z*wb[0].z + xb.w*wb[0].w;
    float p1 = xa.x*wa[1].x + xa.y*wa[1].y + xa.z*wa[1].z + xa.w*wa[1].w
             + xb.x*wb[1].x + xb.y*wb[1].y + xb.z*wb[1].z + xb.w*wb[1].w;
    float p2 = xa.x*wa[2].x + xa.y*wa[2].y + xa.z*wa[2].z + xa.w*wa[2].w
             + xb.x*wb[2].x + xb.y*wb[2].y + xb.z*wb[2].z + xb.w*wb[2].w;
    float p3 = xa.x*wa[3].x + xa.y*wa[3].y + xa.z*wa[3].z + xa.w*wa[3].w
             + xb.x*wb[3].x + xb.y*wb[3].y + xb.z*wb[3].z + xb.w*wb[3].w;
    // quad reduce: q-bit0 <-> lane bit0, q-bit1 <-> lane bit1 (3 shuffles)
    const float a01 = rs_step(p0, p1, b1, 1);
    const float a23 = rs_step(p2, p3, b1, 1);
    part[s] = rs_step(a01, a23, b2, 2);   // q = lane&3, summed over quad
  }

  // cluster reduce-scatter: sample-bit j <-> lane-bit (j+2); bits 4,5 are
  // pure replication groups -> plain xor-add for the last two masks.
  const bool b4 = (lane & 4) != 0;
  const bool b8 = (lane & 8) != 0;
  float a2[2];
  a2[0] = rs_step(part[0], part[1], b4, 4);
  a2[1] = rs_step(part[2], part[3], b4, 4);
  float r = rs_step(a2[0], a2[1], b8, 8);
  r += __shfl_xor(r, 16, 64);
  r += __shfl_xor(r, 32, 64);
  // lane l holds pre-dot for sample (l>>2)&3, output (l&3), replicated x4
  // over lane bits 4,5.

  __syncthreads();   // s_c4/s_s4 ready; also orders s_qout below

  // ---- Phase B: amplitude-per-lane circuit ----
  // lane = g*16 + a: g = sample group (0..3), a = amplitude index.
  // Qubit q lives at bit (3-q) of a.
  const int g = lane >> 4;
  const int a = lane & 15;
  const bool bitp0 = (a & 1) != 0;   // qubit 3
  const bool bitp1 = (a & 2) != 0;   // qubit 2
  const bool bitp2 = (a & 4) != 0;   // qubit 1
  const bool bitp3 = (a & 8) != 0;   // qubit 0

  // angle for slot (a&3) of sample g (r is replicated over bits 4,5)
  constexpr float PI_4 = 0.7853981633974483f;   // theta/2 = tanh*pi/2*0.5
  const float rg = __shfl(r, (g << 2) | (a & 3), 64);
  float sv, cv;
  __sincosf(fast_tanh(rg + bpre_a) * PI_4, &sv, &cv);

  // broadcast the 4 (c,s) pairs of this group: lane (g<<4)|q holds pair q
  float cq[4], sq[4];
  #pragma unroll
  for (int q = 0; q < 4; ++q) {
    const int src = (lane & 48) | q;
    cq[q] = __shfl(cv, src, 64);
    sq[q] = __shfl(sv, src, 64);
  }
  // signed s per lane: RY gives new = c*own + (bit? s : -s)*partner
  const float ss0 = bitp3 ? sq[0] : -sq[0];
  const float ss1 = bitp2 ? sq[1] : -sq[1];
  const float ss2 = bitp1 ? sq[2] : -sq[2];
  const float ss3 = bitp0 ? sq[3] : -sq[3];

  // H^4 then 4 input RYs = product state: f_q = c_q + ss_q, scale 1/4
  float st = (cq[0] + ss0) * (cq[1] + ss1) * ((cq[2] + ss2) * (cq[3] + ss3))
           * 0.25f;

  // 6 layers: CNOT(0,1) CNOT(2,3) CNOT(1,2) then RY x4
  #pragma unroll
  for (int k = 0; k < 6; ++k) {
    // CNOT(C,T): if control bit set, take partner across target bit
    { const float pt = __shfl_xor(st, 4, 64); st = bitp3 ? pt : st; } // C0,T1
    { const float pt = __shfl_xor(st, 1, 64); st = bitp1 ? pt : st; } // C2,T3
    { const float pt = __shfl_xor(st, 2, 64); st = bitp2 ? pt : st; } // C1,T2
    const f4 ck = s_c4[k];
    const f4 sk = s_s4[k];
    { const float pt = __shfl_xor(st, 8, 64);
      st = ck.x * st + (bitp3 ? sk.x : -sk.x) * pt; }                 // RY q0
    { const float pt = __shfl_xor(st, 4, 64);
      st = ck.y * st + (bitp2 ? sk.y : -sk.y) * pt; }                 // RY q1
    { const float pt = __shfl_xor(st, 2, 64);
      st = ck.z * st + (bitp1 ? sk.z : -sk.z) * pt; }                 // RY q2
    { const float pt = __shfl_xor(st, 1, 64);
      st = ck.w * st + (bitp0 ? sk.w : -sk.w) * pt; }                 // RY q3
  }

  // measurement: signed Walsh-Hadamard butterfly over the 4 amplitude bits.
  // After 4 steps lane j holds sum_i (-1)^popc(i&j) p_i; j=8,4,2,1 -> z0..z3.
  float pv = st * st;
  { const float o = __shfl_xor(pv, 1, 64); pv = bitp0 ? (o - pv) : (pv + o); }
  { const float o = __shfl_xor(pv, 2, 64); pv = bitp1 ? (o - pv) : (pv + o); }
  { const float o = __shfl_xor(pv, 4, 64); pv = bitp2 ? (o - pv) : (pv + o); }
  { const float o = __shfl_xor(pv, 8, 64); pv = bitp3 ? (o - pv) : (pv + o); }

  if (__popc(a) == 1) {
    const int q = 3 - __builtin_ctz(a);          // a=8->z0 .. a=1->z3
    ((float*)s_qout)[(wave * WS + g) * 4 + q] = pv;
  }
  __syncthreads();

  // ---- Phase C: post-GEMV, float4 nontemporal stores (800 f4/block) ----
  float* ob = out + (size_t)blockIdx.x * (SPB * 200);
  #pragma unroll
  for (int i = 0; i < 4; ++i) {
    const int idx4 = tid + i * BLOCK;
    if (idx4 < SPB * 50) {
      const int sloc = idx4 / 50;          // magic-div by constant
      const int j4 = idx4 - sloc * 50;     // float4 index within the row
      const f4 qo = s_qout[sloc];
      const f4* wrow = (const f4*)&s_wpost[j4 * 16];
      const float* br = &s_bpost[j4 * 4];
      f4 o;
      o.x = br[0] + wrow[0].x*qo.x + wrow[0].y*qo.y + wrow[0].z*qo.z + wrow[0].w*qo.w;
      o.y = br[1] + wrow[1].x*qo.x + wrow[1].y*qo.y + wrow[1].z*qo.z + wrow[1].w*qo.w;
      o.z = br[2] + wrow[2].x*qo.x + wrow[2].y*qo.y + wrow[2].z*qo.z + wrow[2].w*qo.w;
      o.w = br[3] + wrow[3].x*qo.x + wrow[3].y*qo.y + wrow[3].z*qo.z + wrow[3].w*qo.w;
      __builtin_nontemporal_store(o, (f4*)(ob + (size_t)idx4 * 4));
    }
  }
}

extern "C" void kernel_launch(void* const* d_in, const int* in_sizes, int n_in,
                              void* d_out, int out_size, void* d_ws, size_t ws_size,
                              hipStream_t stream) {
  const float* in    = (const float*)d_in[0];   // [B,512]
  const float* Wpre  = (const float*)d_in[1];   // [4,512]
  const float* bpre  = (const float*)d_in[2];   // [4]
  const float* qp    = (const float*)d_in[3];   // [24]
  const float* Wpost = (const float*)d_in[4];   // [200,4]
  const float* bpost = (const float*)d_in[5];   // [200]
  float* out = (float*)d_out;                   // [B,200]

  const int B = in_sizes[0] / 512;              // 65536
  const int nblk = B / SPB;                     // 4096
  dqnet_kernel<<<nblk, BLOCK, 0, stream>>>(in, Wpre, bpre, qp, Wpost, bpost, out);
}

// Round 4
// 203.345 us; speedup vs baseline: 1.0499x; 1.0499x over previous
//
#include <hip/hip_runtime.h>

// Fused DressedQuantumNet:
//   pre = in[65536,512] @ W_pre.T[512,4] + b_pre          (memory-bound: 134 MB read)
//   q_in = tanh(pre) * pi/2
//   q_out = 4-qubit circuit (16 real amplitudes)
//   out = q_out @ W_post.T[4,200] + b_post                (52 MB write)
//
// Block=256 (4 waves), wave owns 4 samples, grid = B/16 = 4096 (generation
// overlap: young blocks stream Phase-A reads while retiring blocks run B/C).
//
// Phase B is AMPLITUDE-PER-LANE: 16 lanes hold one sample's 16 amplitudes,
// 4 samples per wave -> all 64 lanes busy. RY = shfl_xor + sign-select + fma;
// CNOT = shfl_xor + cndmask; all four <Z_q> via one signed Walsh-Hadamard
// butterfly (4 shfl).
//
// R4 = exact revert to the R2 configuration (best measured: 203.8 us).
// R3's A/B proved the input is NOT L3-resident across iterations (the
// harness poison fills thrash the 256MB Infinity Cache) and that plain
// cacheable input loads cost ~+10us vs nontemporal -> nt loads are optimal.

#define BLOCK 256
#define WS 4             // samples per wave
#define SPB 16           // samples per block

typedef float f4 __attribute__((ext_vector_type(4)));

__device__ __forceinline__ f4 ntload4(const float* p) {
  return __builtin_nontemporal_load((const f4*)p);
}

// tanh(x) = 1 - 2/(exp(2x)+1); hw v_exp + v_rcp. Error ~ulp vs 1.5e-2 budget.
__device__ __forceinline__ float fast_tanh(float x) {
  const float e = __expf(2.0f * x);
  return 1.0f - 2.0f * __builtin_amdgcn_rcpf(e + 1.0f);
}

// One reduce-scatter step at xor-mask m. v0 = copy with bit==0, v1 = bit==1.
// Lane keeps the copy matching (lane&m), sends the other.
__device__ __forceinline__ float rs_step(float v0, float v1, bool hi, int m) {
  const float sd = hi ? v0 : v1;
  const float kp = hi ? v1 : v0;
  return kp + __shfl_xor(sd, m, 64);
}

__global__ __launch_bounds__(BLOCK, 4) void dqnet_kernel(
    const float* __restrict__ in, const float* __restrict__ Wpre,
    const float* __restrict__ bpre, const float* __restrict__ qp,
    const float* __restrict__ Wpost, const float* __restrict__ bpost,
    float* __restrict__ out) {
  __shared__ float s_wpost[200 * 4];   // [j][q]
  __shared__ float s_bpost[200];
  __shared__ f4 s_c4[6], s_s4[6];      // cos/sin(qw[k,q]/2), f4 per layer
  __shared__ f4 s_qout[SPB];           // [sample_local] -> (z0,z1,z2,z3)

  const int tid = threadIdx.x;
  const int lane = tid & 63;
  const int wave = tid >> 6;

  // ---- setup: stage W_post/b_post and circuit-layer sincos into LDS ----
  if (tid < 200) {
    ((f4*)s_wpost)[tid] = ((const f4*)Wpost)[tid];
    s_bpost[tid] = bpost[tid];
  } else if (tid < 224) {
    const int k = tid - 200;
    const float a = qp[k] * 0.5f;
    ((float*)s_c4)[k] = __cosf(a);
    ((float*)s_s4)[k] = __sinf(a);
  }

  // per-lane bias for its angle slot (4 floats, L1-hit)
  const float bpre_a = bpre[lane & 3];

  // Per-lane W_pre fragment: features [lane*4, lane*4+4) and +256.
  f4 wa[4], wb[4];
  #pragma unroll
  for (int q = 0; q < 4; ++q) {
    wa[q] = *(const f4*)(Wpre + q * 512 + lane * 4);
    wb[q] = *(const f4*)(Wpre + q * 512 + 256 + lane * 4);
  }

  // ---- Phase A: pre-GEMV, depth-2 prefetch ring, per-lane partials ----
  const int tile = blockIdx.x * SPB + wave * WS;
  const float* rb = in + (size_t)tile * 512 + lane * 4;

  const bool b1 = (lane & 1) != 0;
  const bool b2 = (lane & 2) != 0;

  float part[WS];
  f4 pxa[2], pxb[2];
  pxa[0] = ntload4(rb);        pxb[0] = ntload4(rb + 256);
  pxa[1] = ntload4(rb + 512);  pxb[1] = ntload4(rb + 512 + 256);
  #pragma unroll
  for (int s = 0; s < WS; ++s) {
    const f4 xa = pxa[s & 1], xb = pxb[s & 1];
    if (s + 2 < WS) {                 // refill ring slot two ahead
      pxa[s & 1] = ntload4(rb + (size_t)(s + 2) * 512);
      pxb[s & 1] = ntload4(rb + (size_t)(s + 2) * 512 + 256);
    }
    float p0 = xa.x*wa[0].x + xa.y*wa[0].y + xa.z*wa[0].z + xa.w*wa[0].w
             + xb.x*wb[0].x + xb.y*wb[0].y + xb.z*wb[0].z + xb.w*wb[0].w;
    float p1 = xa.x*wa[1].x + xa.y*wa[1].y + xa.z*wa[1].z + xa.w*wa[1].w
             + xb.x*wb[1].x + xb.y*wb[1].y + xb.z*wb[1].z + xb.w*wb[1].w;
    float p2 = xa.x*wa[2].x + xa.y*wa[2].y + xa.z*wa[2].z + xa.w*wa[2].w
             + xb.x*wb[2].x + xb.y*wb[2].y + xb.z*wb[2].z + xb.w*wb[2].w;
    float p3 = xa.x*wa[3].x + xa.y*wa[3].y + xa.z*wa[3].z + xa.w*wa[3].w
             + xb.x*wb[3].x + xb.y*wb[3].y + xb.z*wb[3].z + xb.w*wb[3].w;
    // quad reduce: q-bit0 <-> lane bit0, q-bit1 <-> lane bit1 (3 shuffles)
    const float a01 = rs_step(p0, p1, b1, 1);
    const float a23 = rs_step(p2, p3, b1, 1);
    part[s] = rs_step(a01, a23, b2, 2);   // q = lane&3, summed over quad
  }

  // cluster reduce-scatter: sample-bit j <-> lane-bit (j+2); bits 4,5 are
  // pure replication groups -> plain xor-add for the last two masks.
  const bool b4 = (lane & 4) != 0;
  const bool b8 = (lane & 8) != 0;
  float a2[2];
  a2[0] = rs_step(part[0], part[1], b4, 4);
  a2[1] = rs_step(part[2], part[3], b4, 4);
  float r = rs_step(a2[0], a2[1], b8, 8);
  r += __shfl_xor(r, 16, 64);
  r += __shfl_xor(r, 32, 64);
  // lane l holds pre-dot for sample (l>>2)&3, output (l&3), replicated x4
  // over lane bits 4,5.

  __syncthreads();   // s_c4/s_s4 ready; also orders s_qout below

  // ---- Phase B: amplitude-per-lane circuit ----
  // lane = g*16 + a: g = sample group (0..3), a = amplitude index.
  // Qubit q lives at bit (3-q) of a.
  const int g = lane >> 4;
  const int a = lane & 15;
  const bool bitp0 = (a & 1) != 0;   // qubit 3
  const bool bitp1 = (a & 2) != 0;   // qubit 2
  const bool bitp2 = (a & 4) != 0;   // qubit 1
  const bool bitp3 = (a & 8) != 0;   // qubit 0

  // angle for slot (a&3) of sample g (r is replicated over bits 4,5)
  constexpr float PI_4 = 0.7853981633974483f;   // theta/2 = tanh*pi/2*0.5
  const float rg = __shfl(r, (g << 2) | (a & 3), 64);
  float sv, cv;
  __sincosf(fast_tanh(rg + bpre_a) * PI_4, &sv, &cv);

  // broadcast the 4 (c,s) pairs of this group: lane (g<<4)|q holds pair q
  float cq[4], sq[4];
  #pragma unroll
  for (int q = 0; q < 4; ++q) {
    const int src = (lane & 48) | q;
    cq[q] = __shfl(cv, src, 64);
    sq[q] = __shfl(sv, src, 64);
  }
  // signed s per lane: RY gives new = c*own + (bit? s : -s)*partner
  const float ss0 = bitp3 ? sq[0] : -sq[0];
  const float ss1 = bitp2 ? sq[1] : -sq[1];
  const float ss2 = bitp1 ? sq[2] : -sq[2];
  const float ss3 = bitp0 ? sq[3] : -sq[3];

  // H^4 then 4 input RYs = product state: f_q = c_q + ss_q, scale 1/4
  float st = (cq[0] + ss0) * (cq[1] + ss1) * ((cq[2] + ss2) * (cq[3] + ss3))
           * 0.25f;

  // 6 layers: CNOT(0,1) CNOT(2,3) CNOT(1,2) then RY x4
  #pragma unroll
  for (int k = 0; k < 6; ++k) {
    // CNOT(C,T): if control bit set, take partner across target bit
    { const float pt = __shfl_xor(st, 4, 64); st = bitp3 ? pt : st; } // C0,T1
    { const float pt = __shfl_xor(st, 1, 64); st = bitp1 ? pt : st; } // C2,T3
    { const float pt = __shfl_xor(st, 2, 64); st = bitp2 ? pt : st; } // C1,T2
    const f4 ck = s_c4[k];
    const f4 sk = s_s4[k];
    { const float pt = __shfl_xor(st, 8, 64);
      st = ck.x * st + (bitp3 ? sk.x : -sk.x) * pt; }                 // RY q0
    { const float pt = __shfl_xor(st, 4, 64);
      st = ck.y * st + (bitp2 ? sk.y : -sk.y) * pt; }                 // RY q1
    { const float pt = __shfl_xor(st, 2, 64);
      st = ck.z * st + (bitp1 ? sk.z : -sk.z) * pt; }                 // RY q2
    { const float pt = __shfl_xor(st, 1, 64);
      st = ck.w * st + (bitp0 ? sk.w : -sk.w) * pt; }                 // RY q3
  }

  // measurement: signed Walsh-Hadamard butterfly over the 4 amplitude bits.
  // After 4 steps lane j holds sum_i (-1)^popc(i&j) p_i; j=8,4,2,1 -> z0..z3.
  float pv = st * st;
  { const float o = __shfl_xor(pv, 1, 64); pv = bitp0 ? (o - pv) : (pv + o); }
  { const float o = __shfl_xor(pv, 2, 64); pv = bitp1 ? (o - pv) : (pv + o); }
  { const float o = __shfl_xor(pv, 4, 64); pv = bitp2 ? (o - pv) : (pv + o); }
  { const float o = __shfl_xor(pv, 8, 64); pv = bitp3 ? (o - pv) : (pv + o); }

  if (__popc(a) == 1) {
    const int q = 3 - __builtin_ctz(a);          // a=8->z0 .. a=1->z3
    ((float*)s_qout)[(wave * WS + g) * 4 + q] = pv;
  }
  __syncthreads();

  // ---- Phase C: post-GEMV, float4 nontemporal stores (800 f4/block) ----
  float* ob = out + (size_t)blockIdx.x * (SPB * 200);
  #pragma unroll
  for (int i = 0; i < 4; ++i) {
    const int idx4 = tid + i * BLOCK;
    if (idx4 < SPB * 50) {
      const int sloc = idx4 / 50;          // magic-div by constant
      const int j4 = idx4 - sloc * 50;     // float4 index within the row
      const f4 qo = s_qout[sloc];
      const f4* wrow = (const f4*)&s_wpost[j4 * 16];
      const float* br = &s_bpost[j4 * 4];
      f4 o;
      o.x = br[0] + wrow[0].x*qo.x + wrow[0].y*qo.y + wrow[0].z*qo.z + wrow[0].w*qo.w;
      o.y = br[1] + wrow[1].x*qo.x + wrow[1].y*qo.y + wrow[1].z*qo.z + wrow[1].w*qo.w;
      o.z = br[2] + wrow[2].x*qo.x + wrow[2].y*qo.y + wrow[2].z*qo.z + wrow[2].w*qo.w;
      o.w = br[3] + wrow[3].x*qo.x + wrow[3].y*qo.y + wrow[3].z*qo.z + wrow[3].w*qo.w;
      __builtin_nontemporal_store(o, (f4*)(ob + (size_t)idx4 * 4));
    }
  }
}

extern "C" void kernel_launch(void* const* d_in, const int* in_sizes, int n_in,
                              void* d_out, int out_size, void* d_ws, size_t ws_size,
                              hipStream_t stream) {
  const float* in    = (const float*)d_in[0];   // [B,512]
  const float* Wpre  = (const float*)d_in[1];   // [4,512]
  const float* bpre  = (const float*)d_in[2];   // [4]
  const float* qp    = (const float*)d_in[3];   // [24]
  const float* Wpost = (const float*)d_in[4];   // [200,4]
  const float* bpost = (const float*)d_in[5];   // [200]
  float* out = (float*)d_out;                   // [B,200]

  const int B = in_sizes[0] / 512;              // 65536
  const int nblk = B / SPB;                     // 4096
  dqnet_kernel<<<nblk, BLOCK, 0, stream>>>(in, Wpre, bpre, qp, Wpost, bpost, out);
}